// Round 4
// baseline (13898.254 us; speedup 1.0000x reference)
//
#include <hip/hip_runtime.h>
#include <cstdint>
#include <cstddef>

// Model dims
#define T_ 256
#define B_ 128
#define D_ 128
#define H_ 1024
#define K1_ 1152   // D + H
#define K2_ 2048   // 2H
#define NBLK 256   // persistent grid size (1 block/CU, cooperative launch)
#define W1S 1160   // K1 + 8 pad (elems)
#define W2S 2056   // K2 + 8 pad
#define BH_ (B_ * H_)

typedef __bf16 bf16x8 __attribute__((ext_vector_type(8)));
typedef short s8 __attribute__((ext_vector_type(8)));
typedef float f32x4 __attribute__((ext_vector_type(4)));

__device__ __forceinline__ unsigned short f2bf(float f) {
  unsigned int u = __builtin_bit_cast(unsigned int, f);
  u += 0x7fff + ((u >> 16) & 1);   // RNE
  return (unsigned short)(u >> 16);
}
__device__ __forceinline__ float sigm(float x) { return 1.f / (1.f + __expf(-x)); }
__device__ __forceinline__ float tanh_(float x) { return 1.f - 2.f / (__expf(2.f * x) + 1.f); }

__device__ __forceinline__ f32x4 mfma16(s8 a, s8 b, f32x4 c) {
  return __builtin_amdgcn_mfma_f32_16x16x32_bf16(
      __builtin_bit_cast(bf16x8, a), __builtin_bit_cast(bf16x8, b), c, 0, 0, 0);
}

// ---------------------------------------------------------------------------
// Prep: convert inSeq -> bf16, pack outW -> [col][k] bf16, zero states/loss/bar
// ---------------------------------------------------------------------------
__global__ void prep_misc(const float* __restrict__ inSeq,
                          const float* __restrict__ outW,
                          unsigned short* __restrict__ xbf,
                          unsigned short* __restrict__ outWp,
                          unsigned short* __restrict__ h1b,
                          unsigned short* __restrict__ h2all,
                          float* __restrict__ c1, float* __restrict__ c2,
                          float* __restrict__ loss,
                          unsigned* __restrict__ bar)
{
  int i = blockIdx.x * 256 + threadIdx.x;
  if (i < T_ * B_ * D_) xbf[i] = f2bf(inSeq[i]);
  if (i < B_ * H_) {
    c1[i] = 0.f; c2[i] = 0.f;
    h1b[B_ * H_ + i] = 0;     // h1 parity-1 buffer (read at phase 0) = 0
    h2all[i] = 0;             // slot 0 = h2(t=-1) = 0
  }
  if (i < H_ * D_) {          // outWp[c][k] = outW[k][c]
    int c = i >> 10, k = i & 1023;
    outWp[i] = f2bf(outW[(size_t)k * D_ + c]);
  }
  if (i == 0) { loss[0] = 0.f; bar[0] = 0u; bar[1] = 0u; }
}

// ---------------------------------------------------------------------------
// Pack LSTM weights: src fp32 [K][4096] (gate-major cols: i|j|f|o blocks of H)
//   -> dst bf16 [4096][K], dst row = 4*j + g  (gate-interleaved, k-major)
// ---------------------------------------------------------------------------
__global__ void pack_w(const float* __restrict__ src, unsigned short* __restrict__ dst, int K)
{
  __shared__ float tile[64][65];
  int k0 = blockIdx.x * 64, j0 = blockIdx.y * 64, g = blockIdx.z;
  int tid = threadIdx.x;
#pragma unroll
  for (int e = 0; e < 16; ++e) {
    int li = e * 256 + tid;
    int kl = li >> 6, jl = li & 63;
    tile[kl][jl] = src[(size_t)(k0 + kl) * 4096 + g * 1024 + j0 + jl];
  }
  __syncthreads();
#pragma unroll
  for (int e = 0; e < 16; ++e) {
    int li = e * 256 + tid;
    int jl = li >> 6, kl = li & 63;
    dst[(size_t)((j0 + jl) * 4 + g) * K + k0 + kl] = f2bf(tile[kl][jl]);
  }
}

// ---------------------------------------------------------------------------
// Persistent kernel (COOPERATIVE launch), LDS-resident weights.
// 256 blocks x 512 threads, 1 block/CU guaranteed by cooperative launch.
// Block bid owns h-units [4*bid,4*bid+4) (= packed cols [16*bid,16*bid+16))
// of BOTH layers. Wave wid owns batch rows [16*wid,16*wid+16), full K.
// MFMA: A = weights (M=16 packed cols, from LDS), B = state (N=16 batch,
// from global). C layout: row=quad*4+reg = packed col -> lane (quad,l15)
// holds the 4 gates of unit (u0+quad) for batch row (16*wid+l15) in its 4
// acc regs => fully register-local LSTM epilogue.
// ---------------------------------------------------------------------------
__global__ __launch_bounds__(512, 2) void persist_kernel(
    const unsigned short* __restrict__ xbf,
    const unsigned short* __restrict__ W1p,
    const unsigned short* __restrict__ W2p,
    const float* __restrict__ b1,
    const float* __restrict__ b2,
    unsigned short* __restrict__ h1b,
    unsigned short* __restrict__ h2all,
    float* __restrict__ c1,
    float* __restrict__ c2,
    unsigned* bar)
{
  __shared__ unsigned short w1s[16 * W1S];   // 37,120 B
  __shared__ unsigned short w2s[16 * W2S];   // 65,792 B   (total ~103 KB)

  const int bid = blockIdx.x;
  const int tid = threadIdx.x;
  const int wid = tid >> 6, lane = tid & 63;
  const int quad = lane >> 4, l15 = lane & 15;
  const int kseg = quad * 8;
  const int c0 = bid * 16;        // packed col base
  const int u0 = bid * 4;         // h-unit base

  // ---- one-time: stage this block's weight slice into LDS ----
  {
    const int KC1 = K1_ / 8;      // 144 16B-chunks per col
    for (int i = tid; i < 16 * KC1; i += 512) {
      int col = i / KC1, kc = i - col * KC1;
      *(s8*)&w1s[col * W1S + kc * 8] = *(const s8*)(W1p + (size_t)(c0 + col) * K1_ + kc * 8);
    }
    const int KC2 = K2_ / 8;      // 256
    for (int i = tid; i < 16 * KC2; i += 512) {
      int col = i / KC2, kc = i - col * KC2;
      *(s8*)&w2s[col * W2S + kc * 8] = *(const s8*)(W2p + (size_t)(c0 + col) * K2_ + kc * 8);
    }
  }
  // per-lane epilogue constants: this lane owns (batch=16*wid+l15, unit=u0+quad)
  const int ug = u0 + quad;
  const float b1i = b1[ug], b1j = b1[H_ + ug], b1f = b1[2 * H_ + ug], b1o = b1[3 * H_ + ug];
  const float b2i = b2[ug], b2j = b2[H_ + ug], b2f = b2[2 * H_ + ug], b2o = b2[3 * H_ + ug];
  __syncthreads();

  const int brow = wid * 16 + l15;            // batch row (load & epilogue)
  float* c1p = c1 + (size_t)brow * H_ + ug;
  float* c2p = c2 + (size_t)brow * H_ + ug;
  unsigned short* h1o = h1b + (size_t)brow * H_ + ug;
  unsigned short* h2o = h2all + (size_t)brow * H_ + ug;
  const unsigned short* w1a = &w1s[l15 * W1S + kseg];   // A-frag base, layer 1
  const unsigned short* w2a = &w2s[l15 * W2S + kseg];   // A-frag base, layer 2

  unsigned* bar_cnt = bar;
  unsigned* bar_rel = bar + 1;

  for (int p = 0; p <= T_; ++p) {
    // h1(p-1) lives in parity (p-1)&1 == (p+1)&1
    const unsigned short* h1ptr = h1b + (size_t)((p + 1) & 1) * BH_ + (size_t)brow * H_ + kseg;
    const unsigned short* xptr = xbf + (size_t)(p < T_ ? p : T_ - 1) * (B_ * D_) + (size_t)brow * D_ + kseg;
    const unsigned short* h2ptr = h2all + (size_t)(p >= 1 ? p - 1 : 0) * BH_ + (size_t)brow * H_ + kseg;

    f32x4 a1a = {0.f,0.f,0.f,0.f}, a1b = {0.f,0.f,0.f,0.f};
    f32x4 a2a = {0.f,0.f,0.f,0.f}, a2b = {0.f,0.f,0.f,0.f};

    // ---- x segment (L1 only): 4 chunks of K=32 ----
    {
      s8 bx0 = *(const s8*)(xptr);
      s8 bx1 = *(const s8*)(xptr + 32);
      s8 bx2 = *(const s8*)(xptr + 64);
      s8 bx3 = *(const s8*)(xptr + 96);
      a1a = mfma16(*(const s8*)(w1a + 0),  bx0, a1a);
      a1b = mfma16(*(const s8*)(w1a + 32), bx1, a1b);
      a1a = mfma16(*(const s8*)(w1a + 64), bx2, a1a);
      a1b = mfma16(*(const s8*)(w1a + 96), bx3, a1b);
    }
    // ---- h1 segment (shared by L1 k>=128 and L2 k<1024): 32 chunks ----
    {
      s8 st0 = *(const s8*)(h1ptr);
      s8 st1 = *(const s8*)(h1ptr + 32);
      s8 st2 = *(const s8*)(h1ptr + 64);
      s8 st3 = *(const s8*)(h1ptr + 96);
#pragma unroll 4
      for (int kc = 0; kc < 32; ++kc) {
        s8 cur;
        switch (kc & 3) { case 0: cur = st0; break; case 1: cur = st1; break;
                          case 2: cur = st2; break; default: cur = st3; }
        if (kc + 4 < 32) {
          s8 nx = *(const s8*)(h1ptr + (kc + 4) * 32);
          switch (kc & 3) { case 0: st0 = nx; break; case 1: st1 = nx; break;
                            case 2: st2 = nx; break; default: st3 = nx; }
        }
        s8 aL1 = *(const s8*)(w1a + 128 + kc * 32);
        s8 aL2 = *(const s8*)(w2a + kc * 32);
        if (kc & 1) { a1b = mfma16(aL1, cur, a1b); a2b = mfma16(aL2, cur, a2b); }
        else        { a1a = mfma16(aL1, cur, a1a); a2a = mfma16(aL2, cur, a2a); }
      }
    }
    // ---- h2 segment (L2 only): 32 chunks ----
    {
      s8 st0 = *(const s8*)(h2ptr);
      s8 st1 = *(const s8*)(h2ptr + 32);
      s8 st2 = *(const s8*)(h2ptr + 64);
      s8 st3 = *(const s8*)(h2ptr + 96);
#pragma unroll 4
      for (int kc = 0; kc < 32; ++kc) {
        s8 cur;
        switch (kc & 3) { case 0: cur = st0; break; case 1: cur = st1; break;
                          case 2: cur = st2; break; default: cur = st3; }
        if (kc + 4 < 32) {
          s8 nx = *(const s8*)(h2ptr + (kc + 4) * 32);
          switch (kc & 3) { case 0: st0 = nx; break; case 1: st1 = nx; break;
                            case 2: st2 = nx; break; default: st3 = nx; }
        }
        s8 aL2 = *(const s8*)(w2a + 1024 + kc * 32);
        if (kc & 1) a2b = mfma16(aL2, cur, a2b);
        else        a2a = mfma16(aL2, cur, a2a);
      }
    }

    // ---- register-local LSTM epilogues (acc regs = 4 gates of unit ug) ----
    if (p < T_) {
      f32x4 z = a1a + a1b;
      float zi = z[0] + b1i, zj = z[1] + b1j, zf = z[2] + b1f, zo = z[3] + b1o;
      float co = *c1p;
      float cn = co * sigm(zf + 1.0f) + sigm(zi) * tanh_(zj);
      float hn = tanh_(cn) * sigm(zo);
      *c1p = cn;
      h1o[(size_t)(p & 1) * BH_] = f2bf(hn);
    }
    if (p >= 1) {
      f32x4 z = a2a + a2b;
      float zi = z[0] + b2i, zj = z[1] + b2j, zf = z[2] + b2f, zo = z[3] + b2o;
      float co = *c2p;
      float cn = co * sigm(zf + 1.0f) + sigm(zi) * tanh_(zj);
      float hn = tanh_(cn) * sigm(zo);
      *c2p = cn;
      h2o[(size_t)p * BH_] = f2bf(hn);       // slot t+1 = p
    }

    __syncthreads();   // compiler emits vmcnt(0) drain before s_barrier

    // ---- device-wide barrier (monotonic count, release/acquire) ----
    if (tid == 0) {
      __threadfence();                       // wbl2: flush all waves' h/c stores
      unsigned target = (unsigned)(p + 1) * NBLK;
      unsigned a = __hip_atomic_fetch_add(bar_cnt, 1u, __ATOMIC_ACQ_REL,
                                          __HIP_MEMORY_SCOPE_AGENT) + 1u;
      if (a == target) {
        __hip_atomic_store(bar_rel, target, __ATOMIC_RELEASE,
                           __HIP_MEMORY_SCOPE_AGENT);
      } else {
        while (__hip_atomic_load(bar_rel, __ATOMIC_ACQUIRE,
                                 __HIP_MEMORY_SCOPE_AGENT) < target)
          __builtin_amdgcn_s_sleep(1);
      }
      __threadfence();                       // inv: only state/c refetch; weights in LDS
    }
    __syncthreads();
  }
}

// ---------------------------------------------------------------------------
// Tail: logits = h2 @ outW + outB, dual softmax, probs out, CE loss.
// ---------------------------------------------------------------------------
__global__ __launch_bounds__(256, 1) void proj_kernel(
    const unsigned short* __restrict__ h2flat,   // h2all + B*H (slots 1..256)
    const unsigned short* __restrict__ outWp,    // [col][k] bf16
    const float* __restrict__ outB,
    const int* __restrict__ targets,
    float* __restrict__ out,
    float* __restrict__ loss)
{
  __shared__ float lg[128][129];
  __shared__ float red2[256];
  const int r0 = blockIdx.x * 128;
  const int tid = threadIdx.x;
  const int wid = tid >> 6, lane = tid & 63;
  const int quad = lane >> 4, l15 = lane & 15;
  const int wr = (wid & 1) * 64, wc = (wid >> 1) * 64;
  const int kseg = quad * 8;

  f32x4 acc[4][4];
#pragma unroll
  for (int i = 0; i < 4; ++i)
#pragma unroll
    for (int j = 0; j < 4; ++j) acc[i][j] = (f32x4){0.f, 0.f, 0.f, 0.f};

  int arow[4], bcolv[4];
#pragma unroll
  for (int i = 0; i < 4; ++i) arow[i] = r0 + wr + i * 16 + l15;
#pragma unroll
  for (int j = 0; j < 4; ++j) bcolv[j] = wc + j * 16 + l15;

  s8 a[4], b[4], an[4], bn[4];
  auto LD = [&](int kc, s8* A, s8* Bv) {
    int kk = kc * 32 + kseg;
#pragma unroll
    for (int i = 0; i < 4; ++i) A[i] = *(const s8*)(h2flat + (size_t)arow[i] * H_ + kk);
#pragma unroll
    for (int j = 0; j < 4; ++j) Bv[j] = *(const s8*)(outWp + (size_t)bcolv[j] * H_ + kk);
  };
  LD(0, a, b);
  for (int c = 0; c < 32; ++c) {
    if (c + 1 < 32) LD(c + 1, an, bn);
#pragma unroll
    for (int i = 0; i < 4; ++i)
#pragma unroll
      for (int j = 0; j < 4; ++j) acc[i][j] = mfma16(a[i], b[j], acc[i][j]);
#pragma unroll
    for (int i = 0; i < 4; ++i) a[i] = an[i];
#pragma unroll
    for (int j = 0; j < 4; ++j) b[j] = bn[j];
  }

#pragma unroll
  for (int i = 0; i < 4; ++i)
#pragma unroll
    for (int j = 0; j < 4; ++j)
#pragma unroll
      for (int r = 0; r < 4; ++r)
        lg[wr + i * 16 + quad * 4 + r][wc + j * 16 + l15] = acc[i][j][r] + outB[bcolv[j]];
  __syncthreads();

  // dual softmax + CE: 2 threads per row (mel: cols 0..47, har: 48..127)
  const int row = tid >> 1, half = tid & 1;
  const int cbeg = half ? 48 : 0, cend = half ? 128 : 48;
  float m = -1e30f;
  for (int c = cbeg; c < cend; ++c) m = fmaxf(m, lg[row][c]);
  float s = 0.f;
  for (int c = cbeg; c < cend; ++c) s += __expf(lg[row][c] - m);
  float rinv = 1.f / s;
  float* orow = out + (size_t)(r0 + row) * D_;
  for (int c = cbeg; c < cend; ++c) orow[c] = __expf(lg[row][c] - m) * rinv;

  int tg = targets[(size_t)(r0 + row) * 2 + half];
  int tc = half ? (48 + tg) : tg;
  float ce = -(lg[row][tc] - m - logf(s));
  red2[tid] = 0.5f * ce;
  __syncthreads();
  for (int o = 128; o > 0; o >>= 1) {
    if (tid < o) red2[tid] += red2[tid + o];
    __syncthreads();
  }
  if (tid == 0) atomicAdd(loss, red2[0]);
}

__global__ void finalize_loss(const float* __restrict__ loss, float* __restrict__ out)
{
  out[(size_t)T_ * B_ * D_] = loss[0] * (1.f / (float)(T_ * B_));
}

// ---------------------------------------------------------------------------
extern "C" void kernel_launch(void* const* d_in, const int* in_sizes, int n_in,
                              void* d_out, int out_size, void* d_ws, size_t ws_size,
                              hipStream_t stream)
{
  const float* inSeq = (const float*)d_in[0];
  const int* targets = (const int*)d_in[1];
  const float* W1 = (const float*)d_in[2];
  const float* b1 = (const float*)d_in[3];
  const float* W2 = (const float*)d_in[4];
  const float* b2 = (const float*)d_in[5];
  const float* outW = (const float*)d_in[6];
  const float* outB = (const float*)d_in[7];
  float* out = (float*)d_out;

  // workspace layout (~104 MB total)
  char* w = (char*)d_ws;
  auto alloc = [&](size_t bytes) {
    char* r = w;
    w += (bytes + 255) & ~(size_t)255;
    return r;
  };
  unsigned short* W1p = (unsigned short*)alloc((size_t)4096 * K1_ * 2);
  unsigned short* W2p = (unsigned short*)alloc((size_t)4096 * K2_ * 2);
  unsigned short* xbf = (unsigned short*)alloc((size_t)T_ * B_ * D_ * 2);
  unsigned short* h1b = (unsigned short*)alloc((size_t)2 * B_ * H_ * 2);
  unsigned short* h2all = (unsigned short*)alloc((size_t)(T_ + 1) * B_ * H_ * 2);
  float* c1 = (float*)alloc((size_t)B_ * H_ * 4);
  float* c2 = (float*)alloc((size_t)B_ * H_ * 4);
  unsigned short* outWp = (unsigned short*)alloc((size_t)H_ * D_ * 2);
  float* loss = (float*)alloc(256);
  unsigned* bar = (unsigned*)alloc(256);

  prep_misc<<<dim3((T_ * B_ * D_) / 256), dim3(256), 0, stream>>>(
      inSeq, outW, xbf, outWp, h1b, h2all, c1, c2, loss, bar);
  pack_w<<<dim3(K1_ / 64, 16, 4), dim3(256), 0, stream>>>(W1, W1p, K1_);
  pack_w<<<dim3(K2_ / 64, 16, 4), dim3(256), 0, stream>>>(W2, W2p, K2_);

  {
    const unsigned short* xbf_c = xbf;
    const unsigned short* W1p_c = W1p;
    const unsigned short* W2p_c = W2p;
    void* kargs[10] = {
      (void*)&xbf_c, (void*)&W1p_c, (void*)&W2p_c,
      (void*)&b1, (void*)&b2,
      (void*)&h1b, (void*)&h2all, (void*)&c1, (void*)&c2, (void*)&bar
    };
    hipLaunchCooperativeKernel(persist_kernel, dim3(NBLK), dim3(512),
                               kargs, 0, stream);
  }

  proj_kernel<<<dim3(256), dim3(256), 0, stream>>>(
      h2all + (size_t)B_ * H_, outWp, outB, targets, out, loss);
  finalize_loss<<<dim3(1), dim3(1), 0, stream>>>(loss, out);
}

// Round 6
// 6913.155 us; speedup vs baseline: 2.0104x; 2.0104x over previous
//
#include <hip/hip_runtime.h>
#include <cstdint>
#include <cstddef>

// Model dims
#define T_ 256
#define B_ 128
#define D_ 128
#define H_ 1024
#define K1_ 1152   // D + H
#define K2_ 2048   // 2H
#define NBLK 256   // persistent grid size (1 block/CU, cooperative launch)
#define BH_ (B_ * H_)
#define NC1 36     // K1/32 chunks
#define NC2 64     // K2/32 chunks

typedef __bf16 bf16x8 __attribute__((ext_vector_type(8)));
typedef short s8 __attribute__((ext_vector_type(8)));
typedef float f32x4 __attribute__((ext_vector_type(4)));

// agent-scope fences: release = st.wb drain (buffer_wbl2), acquire = buffer_inv
#define FENCE_REL_AGENT() __builtin_amdgcn_fence(__ATOMIC_RELEASE, "agent")
#define FENCE_ACQ_AGENT() __builtin_amdgcn_fence(__ATOMIC_ACQUIRE, "agent")

__device__ __forceinline__ unsigned short f2bf(float f) {
  unsigned int u = __builtin_bit_cast(unsigned int, f);
  u += 0x7fff + ((u >> 16) & 1);   // RNE
  return (unsigned short)(u >> 16);
}
__device__ __forceinline__ float sigm(float x) { return 1.f / (1.f + __expf(-x)); }
__device__ __forceinline__ float tanh_(float x) { return 1.f - 2.f / (__expf(2.f * x) + 1.f); }

__device__ __forceinline__ f32x4 mfma16(s8 a, s8 b, f32x4 c) {
  return __builtin_amdgcn_mfma_f32_16x16x32_bf16(
      __builtin_bit_cast(bf16x8, a), __builtin_bit_cast(bf16x8, b), c, 0, 0, 0);
}

// ---------------------------------------------------------------------------
// Prep: convert inSeq -> bf16, pack outW -> [col][k] bf16, zero states/loss/bar
// ---------------------------------------------------------------------------
__global__ void prep_misc(const float* __restrict__ inSeq,
                          const float* __restrict__ outW,
                          unsigned short* __restrict__ xbf,
                          unsigned short* __restrict__ outWp,
                          unsigned short* __restrict__ h1b,
                          unsigned short* __restrict__ h2all,
                          float* __restrict__ loss,
                          unsigned* __restrict__ bar)
{
  int i = blockIdx.x * 256 + threadIdx.x;
  if (i < T_ * B_ * D_) xbf[i] = f2bf(inSeq[i]);
  if (i < B_ * H_) {
    h1b[B_ * H_ + i] = 0;     // h1 parity-1 buffer (read at phase 0) = 0
    h2all[i] = 0;             // slot 0 = h2(t=-1) = 0
  }
  if (i < H_ * D_) {          // outWp[c][k] = outW[k][c]
    int c = i >> 10, k = i & 1023;
    outWp[i] = f2bf(outW[(size_t)k * D_ + c]);
  }
  if (i < 512) bar[i] = 0u;   // arrival slots + root
  if (i == 0) loss[0] = 0.f;
}

// ---------------------------------------------------------------------------
// Pack LSTM weights: src fp32 [K][4096] (gate-major cols: i|j|f|o blocks of H)
//   -> dst bf16 [4096][K], dst row = 4*j + g  (gate-interleaved, k-major)
// ---------------------------------------------------------------------------
__global__ void pack_w(const float* __restrict__ src, unsigned short* __restrict__ dst, int K)
{
  __shared__ float tile[64][65];
  int k0 = blockIdx.x * 64, j0 = blockIdx.y * 64, g = blockIdx.z;
  int tid = threadIdx.x;
#pragma unroll
  for (int e = 0; e < 16; ++e) {
    int li = e * 256 + tid;
    int kl = li >> 6, jl = li & 63;
    tile[kl][jl] = src[(size_t)(k0 + kl) * 4096 + g * 1024 + j0 + jl];
  }
  __syncthreads();
#pragma unroll
  for (int e = 0; e < 16; ++e) {
    int li = e * 256 + tid;
    int jl = li >> 6, kl = li & 63;
    dst[(size_t)((j0 + jl) * 4 + g) * K + k0 + kl] = f2bf(tile[kl][jl]);
  }
}

// ---------------------------------------------------------------------------
// Persistent kernel (COOPERATIVE launch), LDS-resident weights.
// 256 blocks x 512 threads, 1 block/CU. Block bid owns h-units [4bid,4bid+4)
// (= packed cols [16bid,16bid+16)) of BOTH layers. Wave wid owns batch rows
// [16wid,16wid+16), full K. MFMA: A = weights (LDS), B = state (global).
// C layout: lane (quad,l15) holds the 4 gates of unit (u0+quad) for batch
// row (16wid+l15) => register-local epilogue; c-state lives in 2 VGPRs.
// LDS weight layout: chunk kc (32 K-elems x 16 cols) stored as 64 16B units
// in (quad,col) order => wave ds_read_b128 covers contiguous 1KB (no bank
// conflicts): A-frag addr = chunk*1024B + lane*16B.
// ---------------------------------------------------------------------------
__global__ __launch_bounds__(512, 2) void persist_kernel(
    const unsigned short* __restrict__ xbf,
    const unsigned short* __restrict__ W1p,
    const unsigned short* __restrict__ W2p,
    const float* __restrict__ b1,
    const float* __restrict__ b2,
    unsigned short* __restrict__ h1b,
    unsigned short* __restrict__ h2all,
    unsigned* bar)
{
  __shared__ unsigned short w1s[NC1 * 512];   // 36,864 B
  __shared__ unsigned short w2s[NC2 * 512];   // 65,536 B  (total 100 KB)

  const int bid = blockIdx.x;
  const int tid = threadIdx.x;
  const int wid = tid >> 6, lane = tid & 63;
  const int quad = lane >> 4, l15 = lane & 15;
  const int kseg = quad * 8;
  const int c0 = bid * 16;        // packed col base
  const int u0 = bid * 4;         // h-unit base

  // ---- one-time: stage weights into LDS, swizzled (chunk, quad, col) ----
  for (int i = tid; i < NC1 * 64; i += 512) {
    int c = i >> 6, r = i & 63, q = r >> 4, col = r & 15;
    *(s8*)&w1s[i * 8] = *(const s8*)(W1p + (size_t)(c0 + col) * K1_ + c * 32 + q * 8);
  }
  for (int i = tid; i < NC2 * 64; i += 512) {
    int c = i >> 6, r = i & 63, q = r >> 4, col = r & 15;
    *(s8*)&w2s[i * 8] = *(const s8*)(W2p + (size_t)(c0 + col) * K2_ + c * 32 + q * 8);
  }
  // per-lane epilogue constants: lane owns (batch=16*wid+l15, unit=u0+quad)
  const int ug = u0 + quad;
  const float b1i = b1[ug], b1j = b1[H_ + ug], b1f = b1[2 * H_ + ug], b1o = b1[3 * H_ + ug];
  const float b2i = b2[ug], b2j = b2[H_ + ug], b2f = b2[2 * H_ + ug], b2o = b2[3 * H_ + ug];
  __syncthreads();

  const int brow = wid * 16 + l15;            // batch row (load & epilogue)
  float c1r = 0.f, c2r = 0.f;                 // persistent cell state (regs)
  unsigned short* h1o = h1b + (size_t)brow * H_ + ug;
  unsigned short* h2o = h2all + (size_t)brow * H_ + ug;
  const unsigned short* w1a = &w1s[lane * 8]; // A-frag base (stride 1KB/chunk)
  const unsigned short* w2a = &w2s[lane * 8];

  unsigned* bar_arr = bar;            // 256 arrival slots
  unsigned* bar_root = bar + 288;     // own cache line

  for (int p = 0; p <= T_; ++p) {
    // h1(p-1) lives in parity (p-1)&1 == (p+1)&1
    const unsigned short* h1ptr = h1b + (size_t)((p + 1) & 1) * BH_ + (size_t)brow * H_ + kseg;
    const unsigned short* xptr = xbf + (size_t)(p < T_ ? p : T_ - 1) * (B_ * D_) + (size_t)brow * D_ + kseg;
    const unsigned short* h2ptr = h2all + (size_t)(p >= 1 ? p - 1 : 0) * BH_ + (size_t)brow * H_ + kseg;

    f32x4 a1a = {0.f,0.f,0.f,0.f}, a1b = {0.f,0.f,0.f,0.f};
    f32x4 a2a = {0.f,0.f,0.f,0.f}, a2b = {0.f,0.f,0.f,0.f};

    // ---- x segment (L1 only): chunks 0..3 ----
    {
      s8 bx0 = *(const s8*)(xptr);
      s8 bx1 = *(const s8*)(xptr + 32);
      s8 bx2 = *(const s8*)(xptr + 64);
      s8 bx3 = *(const s8*)(xptr + 96);
      a1a = mfma16(*(const s8*)(w1a + 0 * 512), bx0, a1a);
      a1b = mfma16(*(const s8*)(w1a + 1 * 512), bx1, a1b);
      a1a = mfma16(*(const s8*)(w1a + 2 * 512), bx2, a1a);
      a1b = mfma16(*(const s8*)(w1a + 3 * 512), bx3, a1b);
    }
    // ---- h1 segment (shared by L1 chunks 4..35 and L2 chunks 0..31) ----
    {
      s8 st0 = *(const s8*)(h1ptr);
      s8 st1 = *(const s8*)(h1ptr + 32);
      s8 st2 = *(const s8*)(h1ptr + 64);
      s8 st3 = *(const s8*)(h1ptr + 96);
#pragma unroll 4
      for (int kc = 0; kc < 32; ++kc) {
        s8 cur;
        switch (kc & 3) { case 0: cur = st0; break; case 1: cur = st1; break;
                          case 2: cur = st2; break; default: cur = st3; }
        if (kc + 4 < 32) {
          s8 nx = *(const s8*)(h1ptr + (kc + 4) * 32);
          switch (kc & 3) { case 0: st0 = nx; break; case 1: st1 = nx; break;
                            case 2: st2 = nx; break; default: st3 = nx; }
        }
        s8 aL1 = *(const s8*)(w1a + (4 + kc) * 512);
        s8 aL2 = *(const s8*)(w2a + kc * 512);
        if (kc & 1) { a1b = mfma16(aL1, cur, a1b); a2b = mfma16(aL2, cur, a2b); }
        else        { a1a = mfma16(aL1, cur, a1a); a2a = mfma16(aL2, cur, a2a); }
      }
    }
    // ---- h2 segment (L2 chunks 32..63) ----
    {
      s8 st0 = *(const s8*)(h2ptr);
      s8 st1 = *(const s8*)(h2ptr + 32);
      s8 st2 = *(const s8*)(h2ptr + 64);
      s8 st3 = *(const s8*)(h2ptr + 96);
#pragma unroll 4
      for (int kc = 0; kc < 32; ++kc) {
        s8 cur;
        switch (kc & 3) { case 0: cur = st0; break; case 1: cur = st1; break;
                          case 2: cur = st2; break; default: cur = st3; }
        if (kc + 4 < 32) {
          s8 nx = *(const s8*)(h2ptr + (kc + 4) * 32);
          switch (kc & 3) { case 0: st0 = nx; break; case 1: st1 = nx; break;
                            case 2: st2 = nx; break; default: st3 = nx; }
        }
        s8 aL2 = *(const s8*)(w2a + (32 + kc) * 512);
        if (kc & 1) a2b = mfma16(aL2, cur, a2b);
        else        a2a = mfma16(aL2, cur, a2a);
      }
    }

    // ---- register-local LSTM epilogues ----
    if (p < T_) {
      f32x4 z = a1a + a1b;
      float zi = z[0] + b1i, zj = z[1] + b1j, zf = z[2] + b1f, zo = z[3] + b1o;
      float cn = c1r * sigm(zf + 1.0f) + sigm(zi) * tanh_(zj);
      float hn = tanh_(cn) * sigm(zo);
      c1r = cn;
      h1o[(size_t)(p & 1) * BH_] = f2bf(hn);
    }
    if (p >= 1) {
      f32x4 z = a2a + a2b;
      float zi = z[0] + b2i, zj = z[1] + b2j, zf = z[2] + b2f, zo = z[3] + b2o;
      float cn = c2r * sigm(zf + 1.0f) + sigm(zi) * tanh_(zj);
      float hn = tanh_(cn) * sigm(zo);
      c2r = cn;
      h2o[(size_t)p * BH_] = f2bf(hn);       // slot p holds h2(t=p-1)
    }

    __syncthreads();   // per-wave vmcnt(0): all stores have reached L2

    // ---- device barrier: RMW-free, relaxed polls, 1 wbl2 + 1 inv ----
    const unsigned tgt = (unsigned)(p + 1);
    if (tid == 0) {
      FENCE_REL_AGENT();                     // wbl2: publish h/c stores
      __hip_atomic_store(&bar_arr[bid], tgt, __ATOMIC_RELAXED, __HIP_MEMORY_SCOPE_AGENT);
    }
    if (bid == 0) {
      if (tid < NBLK) {
        while (__hip_atomic_load(&bar_arr[tid], __ATOMIC_RELAXED,
                                 __HIP_MEMORY_SCOPE_AGENT) < tgt)
          __builtin_amdgcn_s_sleep(1);
      }
      __syncthreads();
      if (tid == 0) {
        FENCE_ACQ_AGENT();
        FENCE_REL_AGENT();
        __hip_atomic_store(bar_root, tgt, __ATOMIC_RELAXED, __HIP_MEMORY_SCOPE_AGENT);
      }
      __syncthreads();
    } else {
      if (tid == 0) {
        while (__hip_atomic_load(bar_root, __ATOMIC_RELAXED,
                                 __HIP_MEMORY_SCOPE_AGENT) < tgt)
          __builtin_amdgcn_s_sleep(1);
        FENCE_ACQ_AGENT();                   // inv: refetch state through L2
      }
      __syncthreads();
    }
  }
}

// ---------------------------------------------------------------------------
// Tail: logits = h2 @ outW + outB, dual softmax, probs out, CE loss.
// ---------------------------------------------------------------------------
__global__ __launch_bounds__(256, 1) void proj_kernel(
    const unsigned short* __restrict__ h2flat,   // h2all + B*H (slots 1..256)
    const unsigned short* __restrict__ outWp,    // [col][k] bf16
    const float* __restrict__ outB,
    const int* __restrict__ targets,
    float* __restrict__ out,
    float* __restrict__ loss)
{
  __shared__ float lg[128][129];
  __shared__ float red2[256];
  const int r0 = blockIdx.x * 128;
  const int tid = threadIdx.x;
  const int wid = tid >> 6, lane = tid & 63;
  const int quad = lane >> 4, l15 = lane & 15;
  const int wr = (wid & 1) * 64, wc = (wid >> 1) * 64;
  const int kseg = quad * 8;

  f32x4 acc[4][4];
#pragma unroll
  for (int i = 0; i < 4; ++i)
#pragma unroll
    for (int j = 0; j < 4; ++j) acc[i][j] = (f32x4){0.f, 0.f, 0.f, 0.f};

  int arow[4], bcolv[4];
#pragma unroll
  for (int i = 0; i < 4; ++i) arow[i] = r0 + wr + i * 16 + l15;
#pragma unroll
  for (int j = 0; j < 4; ++j) bcolv[j] = wc + j * 16 + l15;

  s8 a[4], b[4], an[4], bn[4];
  auto LD = [&](int kc, s8* A, s8* Bv) {
    int kk = kc * 32 + kseg;
#pragma unroll
    for (int i = 0; i < 4; ++i) A[i] = *(const s8*)(h2flat + (size_t)arow[i] * H_ + kk);
#pragma unroll
    for (int j = 0; j < 4; ++j) Bv[j] = *(const s8*)(outWp + (size_t)bcolv[j] * H_ + kk);
  };
  LD(0, a, b);
  for (int c = 0; c < 32; ++c) {
    if (c + 1 < 32) LD(c + 1, an, bn);
#pragma unroll
    for (int i = 0; i < 4; ++i)
#pragma unroll
      for (int j = 0; j < 4; ++j) acc[i][j] = mfma16(a[i], b[j], acc[i][j]);
#pragma unroll
    for (int i = 0; i < 4; ++i) a[i] = an[i];
#pragma unroll
    for (int j = 0; j < 4; ++j) b[j] = bn[j];
  }

#pragma unroll
  for (int i = 0; i < 4; ++i)
#pragma unroll
    for (int j = 0; j < 4; ++j)
#pragma unroll
      for (int r = 0; r < 4; ++r)
        lg[wr + i * 16 + quad * 4 + r][wc + j * 16 + l15] = acc[i][j][r] + outB[bcolv[j]];
  __syncthreads();

  // dual softmax + CE: 2 threads per row (mel: cols 0..47, har: 48..127)
  const int row = tid >> 1, half = tid & 1;
  const int cbeg = half ? 48 : 0, cend = half ? 128 : 48;
  float m = -1e30f;
  for (int c = cbeg; c < cend; ++c) m = fmaxf(m, lg[row][c]);
  float s = 0.f;
  for (int c = cbeg; c < cend; ++c) s += __expf(lg[row][c] - m);
  float rinv = 1.f / s;
  float* orow = out + (size_t)(r0 + row) * D_;
  for (int c = cbeg; c < cend; ++c) orow[c] = __expf(lg[row][c] - m) * rinv;

  int tg = targets[(size_t)(r0 + row) * 2 + half];
  int tc = half ? (48 + tg) : tg;
  float ce = -(lg[row][tc] - m - logf(s));
  red2[tid] = 0.5f * ce;
  __syncthreads();
  for (int o = 128; o > 0; o >>= 1) {
    if (tid < o) red2[tid] += red2[tid + o];
    __syncthreads();
  }
  if (tid == 0) atomicAdd(loss, red2[0]);
}

__global__ void finalize_loss(const float* __restrict__ loss, float* __restrict__ out)
{
  out[(size_t)T_ * B_ * D_] = loss[0] * (1.f / (float)(T_ * B_));
}

// ---------------------------------------------------------------------------
extern "C" void kernel_launch(void* const* d_in, const int* in_sizes, int n_in,
                              void* d_out, int out_size, void* d_ws, size_t ws_size,
                              hipStream_t stream)
{
  const float* inSeq = (const float*)d_in[0];
  const int* targets = (const int*)d_in[1];
  const float* W1 = (const float*)d_in[2];
  const float* b1 = (const float*)d_in[3];
  const float* W2 = (const float*)d_in[4];
  const float* b2 = (const float*)d_in[5];
  const float* outW = (const float*)d_in[6];
  const float* outB = (const float*)d_in[7];
  float* out = (float*)d_out;

  // workspace layout (~103 MB total)
  char* w = (char*)d_ws;
  auto alloc = [&](size_t bytes) {
    char* r = w;
    w += (bytes + 255) & ~(size_t)255;
    return r;
  };
  unsigned short* W1p = (unsigned short*)alloc((size_t)4096 * K1_ * 2);
  unsigned short* W2p = (unsigned short*)alloc((size_t)4096 * K2_ * 2);
  unsigned short* xbf = (unsigned short*)alloc((size_t)T_ * B_ * D_ * 2);
  unsigned short* h1b = (unsigned short*)alloc((size_t)2 * B_ * H_ * 2);
  unsigned short* h2all = (unsigned short*)alloc((size_t)(T_ + 1) * B_ * H_ * 2);
  unsigned short* outWp = (unsigned short*)alloc((size_t)H_ * D_ * 2);
  float* loss = (float*)alloc(256);
  unsigned* bar = (unsigned*)alloc(4096);

  prep_misc<<<dim3((T_ * B_ * D_) / 256), dim3(256), 0, stream>>>(
      inSeq, outW, xbf, outWp, h1b, h2all, loss, bar);
  pack_w<<<dim3(K1_ / 64, 16, 4), dim3(256), 0, stream>>>(W1, W1p, K1_);
  pack_w<<<dim3(K2_ / 64, 16, 4), dim3(256), 0, stream>>>(W2, W2p, K2_);

  {
    const unsigned short* xbf_c = xbf;
    const unsigned short* W1p_c = W1p;
    const unsigned short* W2p_c = W2p;
    void* kargs[8] = {
      (void*)&xbf_c, (void*)&W1p_c, (void*)&W2p_c,
      (void*)&b1, (void*)&b2,
      (void*)&h1b, (void*)&h2all, (void*)&bar
    };
    (void)hipLaunchCooperativeKernel(persist_kernel, dim3(NBLK), dim3(512),
                                     kargs, 0, stream);
  }

  proj_kernel<<<dim3(256), dim3(256), 0, stream>>>(
      h2all + (size_t)B_ * H_, outWp, outB, targets, out, loss);
  finalize_loss<<<dim3(1), dim3(1), 0, stream>>>(loss, out);
}